// Round 6
// baseline (495.735 us; speedup 1.0000x reference)
//
#include <hip/hip_runtime.h>

#define EDGES 400000
#define DIM 128

typedef __attribute__((ext_vector_type(8))) short bf16x8;
typedef __attribute__((ext_vector_type(4))) float f32x4;

// fp32 -> bf16 round-to-nearest-even
__device__ __forceinline__ short f2bf(float f) {
    unsigned u = __builtin_bit_cast(unsigned, f);
    unsigned r = (u + 0x7fffu + ((u >> 16) & 1u)) >> 16;
    return (short)r;
}

// Rearrange W1 [768][384] fp32 -> bf16 frag-major for 16x16x32 MFMA B-operand:
// frag (nt, s): lane holds B[k = (lane>>4)*8 + j][n = lane&15], k-step s, n-tile nt.
__global__ void prep_w1(const float* __restrict__ W1, short* __restrict__ W1f) {
    int idx = blockIdx.x * 256 + threadIdx.x;       // 294912 = 48*12*64*8
    int j    = idx & 7;
    int lane = (idx >> 3) & 63;
    int fs   = idx >> 9;                            // nt*12 + s
    int s    = fs % 12;
    int nt   = fs / 12;
    int n = nt * 16 + (lane & 15);
    int k = s * 32 + (lane >> 4) * 8 + j;
    W1f[idx] = f2bf(W1[n * 384 + k]);
}

// M_w=48 (3 M-tiles/wave, afrag = 144 VGPR). Register-ledger from R1/R4/R5:
// launch_bounds min-waves=2 caps arch VGPRs at 128 (R5's spill); min-waves=1
// gives the 256-reg budget that afrag[3] + overhead (~220) fits. HW occupancy
// is then set by VGPR<=256 -> 8 waves/CU = 2 blocks/CU (LDS 110 KB < 160).
// Chunk-PAIR double buffering: 24 barrier iterations. b1/W2 staged in LDS.
__global__ __launch_bounds__(256, 1)
void edge_mlp(const float* __restrict__ x,
              const int*   __restrict__ ei,      // [2][EDGES]
              const float* __restrict__ b1,      // [768]
              const float* __restrict__ W2,      // [768]
              const float* __restrict__ b2p,     // [1]
              const short* __restrict__ W1f,     // frag-major bf16 W1
              float* __restrict__ out)           // [EDGES]
{
    __shared__ short sB[2][24 * 512];            // 2 x 24 KB: chunk-PAIR buffers
    __shared__ float sBias[768];
    __shared__ float sW2[768];

    const int tid  = threadIdx.x;
    const int lane = tid & 63;
    const int wave = tid >> 6;                   // 0..3
    const int m    = lane & 15;
    const int quad = lane >> 4;
    const int eb   = blockIdx.x * 192;

    // ---- async stage chunk-pair 0 (24 frags; each wave issues 6) ----
    #pragma unroll
    for (int jj = 0; jj < 6; ++jj) {
        int f = wave * 6 + jj;                   // frag 0..23
        __builtin_amdgcn_global_load_lds(
            (const __attribute__((address_space(1))) void*)(W1f + (f << 9) + lane * 8),
            (__attribute__((address_space(3))) void*)(&sB[0][f << 9]),
            16, 0, 0);
    }

    // stage epilogue constants (once per block)
    for (int i = tid; i < 768; i += 256) {
        sBias[i] = b1[i];
        sW2[i]   = W2[i];
    }

    // ---- build A fragments: 3 M-tiles x 12 K-steps (144 VGPR) ----
    // lane holds A[m=lane&15][k=quad*8+j]; sections s 0-3 mean, 4-7 prod,
    // 8-11 sqdiff share the same x columns -> each x chunk loaded once.
    bf16x8 afrag[3][12];
    #pragma unroll
    for (int T = 0; T < 3; ++T) {
        int e = eb + wave * 48 + T * 16 + m;
        int ec = e < EDGES ? e : EDGES - 1;      // tail clamp (results discarded)
        const float* r0 = x + (size_t)ei[ec] * DIM;
        const float* r1 = x + (size_t)ei[EDGES + ec] * DIM;
        #pragma unroll
        for (int i = 0; i < 4; ++i) {
            int c = i * 32 + quad * 8;
            float4 a0 = *(const float4*)(r0 + c);
            float4 a1 = *(const float4*)(r0 + c + 4);
            float4 c0 = *(const float4*)(r1 + c);
            float4 c1 = *(const float4*)(r1 + c + 4);
            float t0[8] = {a0.x,a0.y,a0.z,a0.w,a1.x,a1.y,a1.z,a1.w};
            float t1[8] = {c0.x,c0.y,c0.z,c0.w,c1.x,c1.y,c1.z,c1.w};
            bf16x8 fm, fp, fd;
            #pragma unroll
            for (int j = 0; j < 8; ++j) {
                float aa = t0[j], bb = t1[j];
                fm[j] = f2bf((aa + bb) * 0.5f);
                fp[j] = f2bf(aa * bb);
                float dd = aa - bb;
                fd[j] = f2bf(dd * dd);
            }
            afrag[T][i]     = fm;   // mean      -> k in [0,128)
            afrag[T][i + 4] = fp;   // product   -> k in [128,256)
            afrag[T][i + 8] = fd;   // sq. diff  -> k in [256,384)
        }
    }

    float yp[3][4];
    #pragma unroll
    for (int t = 0; t < 3; ++t)
        #pragma unroll
        for (int r = 0; r < 4; ++r) yp[t][r] = 0.f;

    __syncthreads();   // pair 0 staged (vmcnt drain + barrier)

    for (int p = 0; p < 24; ++p) {
        const int cur = p & 1;

        // prefetch next chunk-pair; ~72 MFMAs of cover before the barrier
        if (p + 1 < 24) {
            const short* src = W1f + (size_t)(p + 1) * 12288;
            #pragma unroll
            for (int jj = 0; jj < 6; ++jj) {
                int f = wave * 6 + jj;
                __builtin_amdgcn_global_load_lds(
                    (const __attribute__((address_space(1))) void*)(src + (f << 9) + lane * 8),
                    (__attribute__((address_space(3))) void*)(&sB[cur ^ 1][f << 9]),
                    16, 0, 0);
            }
        }

        #pragma unroll
        for (int c = 0; c < 2; ++c) {            // the two chunks of the pair
            f32x4 acc[3];
            #pragma unroll
            for (int t = 0; t < 3; ++t) acc[t] = (f32x4){0.f, 0.f, 0.f, 0.f};

            const bf16x8* bp = (const bf16x8*)&sB[cur][c * 6144];
            #pragma unroll
            for (int s = 0; s < 12; ++s) {
                bf16x8 bfrag = bp[(s << 6) + lane];   // conflict-free 1 KB frag
                #pragma unroll
                for (int t = 0; t < 3; ++t)
                    acc[t] = __builtin_amdgcn_mfma_f32_16x16x32_bf16(afrag[t][s], bfrag, acc[t], 0, 0, 0);
            }

            // epilogue: D layout — edge-within-tile = quad*4+r, n = lane&15
            int ng = (p * 2 + c) * 16 + m;
            float bias = sBias[ng];
            float w2v  = sW2[ng];
            #pragma unroll
            for (int t = 0; t < 3; ++t)
                #pragma unroll
                for (int r = 0; r < 4; ++r)
                    yp[t][r] = fmaf(fmaxf(acc[t][r] + bias, 0.f), w2v, yp[t][r]);
        }

        __syncthreads();
    }

    // reduce over the 16 n-lanes (m nibble) of each quad-group
    #pragma unroll
    for (int off = 8; off >= 1; off >>= 1)
        #pragma unroll
        for (int t = 0; t < 3; ++t)
            #pragma unroll
            for (int r = 0; r < 4; ++r)
                yp[t][r] += __shfl_xor(yp[t][r], off, 64);

    if (m == 0) {
        float b2v = b2p[0];
        #pragma unroll
        for (int t = 0; t < 3; ++t) {
            int e0 = eb + wave * 48 + t * 16 + quad * 4;
            #pragma unroll
            for (int r = 0; r < 4; ++r)
                if (e0 + r < EDGES) out[e0 + r] = yp[t][r] + b2v;
        }
    }
}

extern "C" void kernel_launch(void* const* d_in, const int* in_sizes, int n_in,
                              void* d_out, int out_size, void* d_ws, size_t ws_size,
                              hipStream_t stream) {
    const float* x  = (const float*)d_in[0];
    const int*   ei = (const int*)  d_in[1];
    const float* W1 = (const float*)d_in[5];
    const float* b1 = (const float*)d_in[6];
    const float* W2 = (const float*)d_in[7];
    const float* b2 = (const float*)d_in[8];
    short* W1f = (short*)d_ws;                 // 589824 B frag-major bf16 W1
    float* out = (float*)d_out;

    prep_w1<<<1152, 256, 0, stream>>>(W1, W1f);
    edge_mlp<<<2084, 256, 0, stream>>>(x, ei, b1, W2, b2, W1f, out);  // ceil(400000/192)
}